// Round 7
// baseline (275.093 us; speedup 1.0000x reference)
//
#include <hip/hip_runtime.h>
#include <hip/hip_bf16.h>
#include <math.h>

typedef __bf16 bf16;
typedef __attribute__((ext_vector_type(8))) __bf16 bf16x8;
typedef __attribute__((ext_vector_type(4))) __bf16 bf16x4;
typedef __attribute__((ext_vector_type(4))) float f32x4;

#define MFMA16(a,b,c) __builtin_amdgcn_mfma_f32_16x16x32_bf16(a,b,c,0,0,0)

// Problem constants
#define BATCH 2
#define SEQ   2048
#define DMODEL 768
#define NH    12
#define NKV   4
#define NREP  3
#define HD    64
#define FFDIM 2048
#define ROWS  (BATCH*SEQ)   // 4096

// Q pre-scale: 1/sqrt(64) * log2(e)  (softmax runs in exp2 domain)
#define QSCALE 0.18033688011112042f
#define LOG2E  1.4426950408889634f

// async global->LDS 16B copy (wave-uniform LDS base + lane*16 — layout must be contiguous)
__device__ __forceinline__ void gl2lds16(const bf16* g, bf16* l) {
  __builtin_amdgcn_global_load_lds(
      (const __attribute__((address_space(1))) void*)g,
      (__attribute__((address_space(3))) void*)l, 16, 0, 0);
}

__device__ __forceinline__ bf16x8 pack8(f32x4 a, f32x4 b) {
  bf16x8 o;
  o[0] = (bf16)a[0]; o[1] = (bf16)a[1]; o[2] = (bf16)a[2]; o[3] = (bf16)a[3];
  o[4] = (bf16)b[0]; o[5] = (bf16)b[1]; o[6] = (bf16)b[2]; o[7] = (bf16)b[3];
  return o;
}

// ---------------- RoPE cos/sin table: tab[0..65535]=cos[j][s], tab[65536..]=sin[j][s] ----------------
__global__ __launch_bounds__(256) void rope_tab_kernel(float* __restrict__ tab) {
  int id = blockIdx.x * 256 + threadIdx.x;    // 65536 = 32 j * 2048 s
  int j = id >> 11, s = id & 2047;
  float inv = expf(-(float)j * (9.210340371976184f / 32.0f));
  float ang = (float)s * inv;
  tab[id] = cosf(ang);
  tab[65536 + id] = sinf(ang);
}

// ---------------- RMSNorm (vectorized f32x4, 192 threads) ----------------
__global__ __launch_bounds__(192) void rmsnorm_kernel(const float* __restrict__ x,
    const float* __restrict__ g, bf16* __restrict__ out) {
  int row = blockIdx.x;
  const float* xr = x + (size_t)row * DMODEL;
  int t = threadIdx.x;
  f32x4 v = *(const f32x4*)(xr + t * 4);
  float ss = v[0] * v[0] + v[1] * v[1] + v[2] * v[2] + v[3] * v[3];
  #pragma unroll
  for (int off = 32; off; off >>= 1) ss += __shfl_xor(ss, off, 64);
  __shared__ float red[3];
  if ((t & 63) == 0) red[t >> 6] = ss;
  __syncthreads();
  float total = red[0] + red[1] + red[2];
  float norm = sqrtf(total) * 0.03608439182435161f;  // 768^-0.5
  float sc = 1.0f / (norm + 1e-6f);
  f32x4 gv = *(const f32x4*)(g + t * 4);
  bf16x4 o;
  #pragma unroll
  for (int i = 0; i < 4; ++i) o[i] = (bf16)(gv[i] * v[i] * sc);
  *(bf16x4*)(out + (size_t)row * DMODEL + t * 4) = o;
}

// ---------------- Split-K GEMM 64x128 (fp32 B, in-staging cvt): P[s] = A@B^T chunk ----------
__global__ __launch_bounds__(256) void gemm_split_kernel(const bf16* __restrict__ A,
    const float* __restrict__ Bf, float* __restrict__ P, int N, int Ktot, int KCHUNK) {
  __shared__ __align__(16) bf16 At[64 * 32];    // 4KB
  __shared__ __align__(16) bf16 Bt[128 * 32];   // 8KB
  int t = threadIdx.x;
  int lane = t & 63;
  int wave = t >> 6;
  int l15 = lane & 15, lq = lane >> 4;
  int wrow = (wave >> 1) * 32, wcol = (wave & 1) * 64;
  int row0 = blockIdx.y * 64;
  int col0 = blockIdx.x * 128;
  int s = blockIdx.z;
  int kbeg = s * KCHUNK;
  int klen = KCHUNK;                             // Ktot divisible by KCHUNK here
  int srow = t >> 2, sseg = (t & 3) * 8;
  const bf16* Ag0 = A + (size_t)(row0 + srow) * Ktot + kbeg + sseg;
  const float* Bg0 = Bf + (size_t)(col0 + srow) * Ktot + kbeg + sseg;
  const float* Bg1 = Bg0 + (size_t)64 * Ktot;
  bf16* Al0 = At + t * 8;
  bf16* Bl0 = Bt + t * 8;
  bf16* Bl1 = Bt + 2048 + t * 8;

  f32x4 b0a = *(const f32x4*)(Bg0), b0b = *(const f32x4*)(Bg0 + 4);
  f32x4 b1a = *(const f32x4*)(Bg1), b1b = *(const f32x4*)(Bg1 + 4);

  f32x4 zero = {0.f, 0.f, 0.f, 0.f};
  f32x4 acc[2][4];
  #pragma unroll
  for (int m = 0; m < 2; ++m)
    #pragma unroll
    for (int n = 0; n < 4; ++n) acc[m][n] = zero;

  for (int k0 = 0; k0 < klen; k0 += 32) {
    __syncthreads();
    gl2lds16(Ag0 + k0, Al0);
    *(bf16x8*)Bl0 = pack8(b0a, b0b);
    *(bf16x8*)Bl1 = pack8(b1a, b1b);
    if (k0 + 32 < klen) {
      b0a = *(const f32x4*)(Bg0 + k0 + 32); b0b = *(const f32x4*)(Bg0 + k0 + 36);
      b1a = *(const f32x4*)(Bg1 + k0 + 32); b1b = *(const f32x4*)(Bg1 + k0 + 36);
    }
    __syncthreads();
    bf16x8 af[2], bfr[4];
    #pragma unroll
    for (int m = 0; m < 2; ++m)
      af[m] = *(const bf16x8*)(At + (wrow + m * 16 + l15) * 32 + lq * 8);
    #pragma unroll
    for (int n = 0; n < 4; ++n)
      bfr[n] = *(const bf16x8*)(Bt + (wcol + n * 16 + l15) * 32 + lq * 8);
    #pragma unroll
    for (int m = 0; m < 2; ++m)
      #pragma unroll
      for (int n = 0; n < 4; ++n)
        acc[m][n] = MFMA16(af[m], bfr[n], acc[m][n]);
  }
  float* Ps = P + (size_t)s * ROWS * N;
  #pragma unroll
  for (int m = 0; m < 2; ++m)
    #pragma unroll
    for (int n = 0; n < 4; ++n)
      #pragma unroll
      for (int r = 0; r < 4; ++r) {
        size_t idx = (size_t)(row0 + wrow + m * 16 + lq * 4 + r) * N
                   + (col0 + wcol + n * 16 + l15);
        Ps[idx] = acc[m][n][r];
      }
}

// ---------------- Split-K reduce: O = R + sum_s P[s]  (f32x4) ----------------
template<int S>
__global__ __launch_bounds__(256) void reduce_kernel(const float* __restrict__ P,
    const float* __restrict__ R, float* __restrict__ O) {
  const size_t stride4 = (size_t)ROWS * DMODEL / 4;
  size_t i = (size_t)blockIdx.x * 256 + threadIdx.x;   // 786432 exact
  f32x4 acc = ((const f32x4*)R)[i];
  #pragma unroll
  for (int s = 0; s < S; ++s) acc += ((const f32x4*)P)[s * stride4 + i];
  ((f32x4*)O)[i] = acc;
}

// ---------------- QKV GEMM (fp32 W) + fused RoPE epilogue -> Qh/Kh/Vt ----------
__global__ __launch_bounds__(256) void gemm_qkv_kernel(const bf16* __restrict__ A,
    const float* __restrict__ Wq, const float* __restrict__ Wk, const float* __restrict__ Wv,
    const float* __restrict__ tab, bf16* __restrict__ Qh, bf16* __restrict__ Kh,
    bf16* __restrict__ Vt) {
  __shared__ __align__(16) bf16 At[64 * 32];
  __shared__ __align__(16) bf16 Bt[128 * 32];
  const int K = DMODEL;
  int t = threadIdx.x;
  int lane = t & 63, wave = t >> 6;
  int l15 = lane & 15, lq = lane >> 4;
  int wrow = (wave >> 1) * 32, wcol = (wave & 1) * 64;
  int row0 = blockIdx.y * 64;
  int col0 = blockIdx.x * 128;
  int srow = t >> 2, sseg = (t & 3) * 8;

  const float* Bsrc; int brow;
  if (col0 < 768)       { Bsrc = Wq; brow = col0; }
  else if (col0 < 1024) { Bsrc = Wk; brow = col0 - 768; }
  else                  { Bsrc = Wv; brow = col0 - 1024; }

  const bf16* Ag0 = A + (size_t)(row0 + srow) * K + sseg;
  const float* Bg0 = Bsrc + (size_t)(brow + srow) * K + sseg;
  const float* Bg1 = Bg0 + (size_t)64 * K;
  bf16* Al0 = At + t * 8;
  bf16* Bl0 = Bt + t * 8;
  bf16* Bl1 = Bt + 2048 + t * 8;

  f32x4 b0a = *(const f32x4*)(Bg0), b0b = *(const f32x4*)(Bg0 + 4);
  f32x4 b1a = *(const f32x4*)(Bg1), b1b = *(const f32x4*)(Bg1 + 4);

  f32x4 zero = {0.f, 0.f, 0.f, 0.f};
  f32x4 acc[2][4];
  #pragma unroll
  for (int m = 0; m < 2; ++m)
    #pragma unroll
    for (int n = 0; n < 4; ++n) acc[m][n] = zero;

  for (int k0 = 0; k0 < K; k0 += 32) {
    __syncthreads();
    gl2lds16(Ag0 + k0, Al0);
    *(bf16x8*)Bl0 = pack8(b0a, b0b);
    *(bf16x8*)Bl1 = pack8(b1a, b1b);
    if (k0 + 32 < K) {
      b0a = *(const f32x4*)(Bg0 + k0 + 32); b0b = *(const f32x4*)(Bg0 + k0 + 36);
      b1a = *(const f32x4*)(Bg1 + k0 + 32); b1b = *(const f32x4*)(Bg1 + k0 + 36);
    }
    __syncthreads();
    bf16x8 af[2], bfr[4];
    #pragma unroll
    for (int m = 0; m < 2; ++m)
      af[m] = *(const bf16x8*)(At + (wrow + m * 16 + l15) * 32 + lq * 8);
    #pragma unroll
    for (int n = 0; n < 4; ++n)
      bfr[n] = *(const bf16x8*)(Bt + (wcol + n * 16 + l15) * 32 + lq * 8);
    #pragma unroll
    for (int m = 0; m < 2; ++m)
      #pragma unroll
      for (int n = 0; n < 4; ++n)
        acc[m][n] = MFMA16(af[m], bfr[n], acc[m][n]);
  }

  // ---- epilogue: RoPE (Q,K) / transpose-store (V) ----
  int b = row0 >> 11;
  int s0 = (row0 & 2047) + wrow + lq * 4;       // + m*16 + r
  int colw = col0 + wcol;                        // 64-aligned -> one head
  if (colw < 768) {
    int h = colw >> 6;
    f32x4 cv[2][2], sv[2][2];                    // [m][j-half]
    #pragma unroll
    for (int m = 0; m < 2; ++m)
      #pragma unroll
      for (int jh = 0; jh < 2; ++jh) {
        const float* cp = tab + (jh * 16 + l15) * 2048 + s0 + m * 16;
        cv[m][jh] = *(const f32x4*)cp;
        sv[m][jh] = *(const f32x4*)(cp + 65536);
      }
    #pragma unroll
    for (int m = 0; m < 2; ++m)
      #pragma unroll
      for (int n = 0; n < 4; ++n) {
        float sgn = (n < 2) ? -1.f : 1.f;
        #pragma unroll
        for (int r = 0; r < 4; ++r) {
          float c = cv[m][n & 1][r], si = sv[m][n & 1][r];
          float rp = (acc[m][n][r] * c + sgn * acc[m][n ^ 2][r] * si) * QSCALE;
          Qh[((size_t)(b * NH + h) * SEQ + s0 + m * 16 + r) * 64 + n * 16 + l15] = (bf16)rp;
        }
      }
  } else if (colw < 1024) {
    int kh = (colw - 768) >> 6;
    f32x4 cv[2][2], sv[2][2];
    #pragma unroll
    for (int m = 0; m < 2; ++m)
      #pragma unroll
      for (int jh = 0; jh < 2; ++jh) {
        const float* cp = tab + (jh * 16 + l15) * 2048 + s0 + m * 16;
        cv[m][jh] = *(const f32x4*)cp;
        sv[m][jh] = *(const f32x4*)(cp + 65536);
      }
    #pragma unroll
    for (int m = 0; m < 2; ++m)
      #pragma unroll
      for (int n = 0; n < 4; ++n) {
        float sgn = (n < 2) ? -1.f : 1.f;
        #pragma unroll
        for (int r = 0; r < 4; ++r) {
          float c = cv[m][n & 1][r], si = sv[m][n & 1][r];
          float rp = acc[m][n][r] * c + sgn * acc[m][n ^ 2][r] * si;
          Kh[((size_t)(b * NKV + kh) * SEQ + s0 + m * 16 + r) * 64 + n * 16 + l15] = (bf16)rp;
        }
      }
  } else {
    int vh = (colw - 1024) >> 6;
    #pragma unroll
    for (int m = 0; m < 2; ++m)
      #pragma unroll
      for (int n = 0; n < 4; ++n) {
        bf16x4 pv;
        #pragma unroll
        for (int r = 0; r < 4; ++r) pv[r] = (bf16)acc[m][n][r];
        *(bf16x4*)(Vt + ((size_t)(b * NKV + vh) * 64 + n * 16 + l15) * SEQ + s0 + m * 16) = pv;
      }
  }
}

// ---------------- Fused gate/up GEMM (fp32 W) + silu: H = silu(A@Wg^T)*(A@Wu^T) ----------
__global__ __launch_bounds__(256) void gemm_gu_kernel(const bf16* __restrict__ A,
    const float* __restrict__ Wg, const float* __restrict__ Wu, bf16* __restrict__ H) {
  __shared__ __align__(16) bf16 At[128 * 32];   // 8KB
  __shared__ __align__(16) bf16 Bgt[64 * 32];   // 4KB
  __shared__ __align__(16) bf16 But[64 * 32];   // 4KB
  const int K = DMODEL;
  int t = threadIdx.x;
  int lane = t & 63, wave = t >> 6;
  int l15 = lane & 15, lq = lane >> 4;
  int wrow = (wave >> 1) * 64, wcol = (wave & 1) * 32;
  int row0 = blockIdx.y * 128;
  int col0 = blockIdx.x * 64;
  int srow = t >> 2, sseg = (t & 3) * 8;
  const bf16* Ag0 = A + (size_t)(row0 + srow) * K + sseg;
  const bf16* Ag1 = Ag0 + (size_t)64 * K;
  const float* Gg = Wg + (size_t)(col0 + srow) * K + sseg;
  const float* Ug = Wu + (size_t)(col0 + srow) * K + sseg;
  bf16* Al0 = At + t * 8;
  bf16* Al1 = At + 2048 + t * 8;
  bf16* Bgd = Bgt + t * 8;
  bf16* Bud = But + t * 8;

  f32x4 ga = *(const f32x4*)(Gg), gb = *(const f32x4*)(Gg + 4);
  f32x4 ua = *(const f32x4*)(Ug), ub = *(const f32x4*)(Ug + 4);

  f32x4 zero = {0.f, 0.f, 0.f, 0.f};
  f32x4 ag[4][2], au[4][2];
  #pragma unroll
  for (int m = 0; m < 4; ++m)
    #pragma unroll
    for (int n = 0; n < 2; ++n) { ag[m][n] = zero; au[m][n] = zero; }

  for (int k0 = 0; k0 < K; k0 += 32) {
    __syncthreads();
    gl2lds16(Ag0 + k0, Al0);
    gl2lds16(Ag1 + k0, Al1);
    *(bf16x8*)Bgd = pack8(ga, gb);
    *(bf16x8*)Bud = pack8(ua, ub);
    if (k0 + 32 < K) {
      ga = *(const f32x4*)(Gg + k0 + 32); gb = *(const f32x4*)(Gg + k0 + 36);
      ua = *(const f32x4*)(Ug + k0 + 32); ub = *(const f32x4*)(Ug + k0 + 36);
    }
    __syncthreads();
    bf16x8 af[4], bg[2], bu[2];
    #pragma unroll
    for (int m = 0; m < 4; ++m)
      af[m] = *(const bf16x8*)(At + (wrow + m * 16 + l15) * 32 + lq * 8);
    #pragma unroll
    for (int n = 0; n < 2; ++n) {
      bg[n] = *(const bf16x8*)(Bgt + (wcol + n * 16 + l15) * 32 + lq * 8);
      bu[n] = *(const bf16x8*)(But + (wcol + n * 16 + l15) * 32 + lq * 8);
    }
    #pragma unroll
    for (int m = 0; m < 4; ++m)
      #pragma unroll
      for (int n = 0; n < 2; ++n) {
        ag[m][n] = MFMA16(af[m], bg[n], ag[m][n]);
        au[m][n] = MFMA16(af[m], bu[n], au[m][n]);
      }
  }
  #pragma unroll
  for (int m = 0; m < 4; ++m)
    #pragma unroll
    for (int n = 0; n < 2; ++n)
      #pragma unroll
      for (int r = 0; r < 4; ++r) {
        int row = row0 + wrow + m * 16 + lq * 4 + r;
        int col = col0 + wcol + n * 16 + l15;
        float g = ag[m][n][r], u = au[m][n][r];
        float sg = g / (1.f + __builtin_amdgcn_exp2f(-g * LOG2E));
        H[(size_t)row * FFDIM + col] = (bf16)(sg * u);
      }
}

// ---------------- Flash attention: S-transpose + fixed-max softmax ----------
__global__ __launch_bounds__(256) void attn_kernel(const bf16* __restrict__ Qh,
    const bf16* __restrict__ Kh, const bf16* __restrict__ Vt, bf16* __restrict__ out) {
  __shared__ __align__(16) bf16 Kl0[64 * 32];
  __shared__ __align__(16) bf16 Kl1[64 * 32];
  __shared__ __align__(16) bf16 Vl0[64 * 32];
  __shared__ __align__(16) bf16 Vl1[64 * 32];
  __shared__ __align__(16) bf16 P[4][16 * 80];

  int idx = blockIdx.x;
  int qt = 31 - (idx / 24);
  int bh = idx % 24;
  int q0blk = qt * 64;
  int b = bh / NH, h = bh % NH;
  int kvh = h / NREP;
  int t = threadIdx.x;
  int lane = t & 63, wave = t >> 6;
  int l15 = lane & 15, lq = lane >> 4;
  int qw = q0blk + wave * 16;
  const bf16* Qb = Qh + (size_t)(b * NH + h) * SEQ * 64;
  const bf16* Kb = Kh + (size_t)(b * NKV + kvh) * SEQ * 64;
  const bf16* Vb = Vt + (size_t)(b * NKV + kvh) * 64 * SEQ;

  bf16x8 bq0 = *(const bf16x8*)(Qb + (size_t)(qw + l15) * 64 + lq * 8);
  bf16x8 bq1 = *(const bf16x8*)(Qb + (size_t)(qw + l15) * 64 + 32 + lq * 8);

  const bf16* Kg = Kb + (size_t)(t >> 2) * 64 + (t & 3) * 8;
  const bf16* Vg = Vb + (size_t)(t >> 2) * SEQ + (t & 3) * 8;
  bf16* Kl0d = Kl0 + t * 8;
  bf16* Kl1d = Kl1 + t * 8;
  bf16* Vl0d = Vl0 + t * 8;
  bf16* Vl1d = Vl1 + t * 8;
  bf16* Pw = P[wave];
  int Pwq = l15 * 80, lq8 = lq * 8, lq4 = lq * 4;

  f32x4 zero = {0.f, 0.f, 0.f, 0.f};
  f32x4 o[4];
  o[0] = zero; o[1] = zero; o[2] = zero; o[3] = zero;
  float l_r = 0.f;

  for (int k0 = 0; k0 <= q0blk + 63; k0 += 64) {
    __syncthreads();
    gl2lds16(Kg + (size_t)k0 * 64, Kl0d);
    gl2lds16(Kg + (size_t)k0 * 64 + 32, Kl1d);
    gl2lds16(Vg + k0, Vl0d);
    gl2lds16(Vg + k0 + 32, Vl1d);
    __syncthreads();
    f32x4 s[4];
    #pragma unroll
    for (int c = 0; c < 4; ++c) {
      bf16x8 ak0 = *(const bf16x8*)(Kl0 + (c * 16 + l15) * 32 + lq8);
      bf16x8 ak1 = *(const bf16x8*)(Kl1 + (c * 16 + l15) * 32 + lq8);
      s[c] = zero;
      s[c] = MFMA16(ak0, bq0, s[c]);
      s[c] = MFMA16(ak1, bq1, s[c]);
    }
    if (k0 + 63 > qw) {
      int qmk = qw + l15 - k0 - lq4;
      #pragma unroll
      for (int c = 0; c < 4; ++c)
        #pragma unroll
        for (int r = 0; r < 4; ++r)
          if (c * 16 + r > qmk) s[c][r] = -INFINITY;
    }
    #pragma unroll
    for (int c = 0; c < 4; ++c) {
      bf16x4 pe;
      #pragma unroll
      for (int r = 0; r < 4; ++r) {
        float e = __builtin_amdgcn_exp2f(s[c][r]);
        l_r += e;
        pe[r] = (bf16)e;
      }
      *(bf16x4*)(Pw + Pwq + c * 16 + lq4) = pe;
    }
    bf16x8 bp0 = *(const bf16x8*)(Pw + Pwq + lq8);
    bf16x8 bp1 = *(const bf16x8*)(Pw + Pwq + 32 + lq8);
    #pragma unroll
    for (int n = 0; n < 4; ++n) {
      bf16x8 av0 = *(const bf16x8*)(Vl0 + (n * 16 + l15) * 32 + lq8);
      bf16x8 av1 = *(const bf16x8*)(Vl1 + (n * 16 + l15) * 32 + lq8);
      o[n] = MFMA16(av0, bp0, o[n]);
      o[n] = MFMA16(av1, bp1, o[n]);
    }
  }
  float lt = l_r;
  lt += __shfl_xor(lt, 16, 64);
  lt += __shfl_xor(lt, 32, 64);
  float inv = 1.f / lt;
  int q = qw + l15;
  bf16* orow = out + (size_t)(b * SEQ + q) * DMODEL + h * 64;
  #pragma unroll
  for (int n = 0; n < 4; ++n) {
    bf16x4 po;
    #pragma unroll
    for (int r = 0; r < 4; ++r) po[r] = (bf16)(o[n][r] * inv);
    *(bf16x4*)(orow + n * 16 + lq4) = po;
  }
}

extern "C" void kernel_launch(void* const* d_in, const int* in_sizes, int n_in,
                              void* d_out, int out_size, void* d_ws, size_t ws_size,
                              hipStream_t stream) {
  const float* x     = (const float*)d_in[0];
  const float* Wq    = (const float*)d_in[1];
  const float* Wk    = (const float*)d_in[2];
  const float* Wv    = (const float*)d_in[3];
  const float* Wo    = (const float*)d_in[4];
  const float* Wgate = (const float*)d_in[5];
  const float* Wup   = (const float*)d_in[6];
  const float* Wdown = (const float*)d_in[7];
  const float* g1    = (const float*)d_in[8];
  const float* g2    = (const float*)d_in[9];
  float* out = (float*)d_out;

  char* ws = (char*)d_ws;
  size_t off = 0;
  auto alloc = [&](size_t bytes) { size_t o = off; off += (bytes + 255) & ~(size_t)255; return o; };
  size_t o_tab = alloc((size_t)2 * 32 * 2048 * 4);          // 512KB cos/sin
  size_t o_x1  = alloc((size_t)4096 * 768 * 4);
  size_t o_xn  = alloc((size_t)4096 * 768 * 2);
  size_t arena = alloc((size_t)67108864);                   // phase-shared 64MB
  // attention phase layout
  size_t o_Qh  = arena;
  size_t o_Kh  = o_Qh + (size_t)6291456;
  size_t o_Vt  = o_Kh + (size_t)2097152;
  size_t o_ao  = o_Vt + (size_t)2097152;
  size_t o_Pwo = arena + (size_t)16777216;                  // 2 x 12.58MB
  // ffn phase layout (overlaps attention buffers — phases are disjoint)
  size_t o_H   = arena;
  size_t o_Pdn = arena + (size_t)16777216;                  // 4 x 12.58MB
  if (ws_size < off) return;

  float* tab  = (float*)(ws + o_tab);
  float* fx1  = (float*)(ws + o_x1);
  bf16* bxn   = (bf16*)(ws + o_xn);
  bf16* bQh   = (bf16*)(ws + o_Qh);
  bf16* bKh   = (bf16*)(ws + o_Kh);
  bf16* bVt   = (bf16*)(ws + o_Vt);
  bf16* bao   = (bf16*)(ws + o_ao);
  float* Pwo  = (float*)(ws + o_Pwo);
  bf16* bH    = (bf16*)(ws + o_H);
  float* Pdn  = (float*)(ws + o_Pdn);

  rope_tab_kernel<<<256, 256, 0, stream>>>(tab);

  // Attention sublayer
  rmsnorm_kernel<<<4096, 192, 0, stream>>>(x, g1, bxn);
  gemm_qkv_kernel<<<dim3(10, 64), 256, 0, stream>>>(bxn, Wq, Wk, Wv, tab, bQh, bKh, bVt);
  attn_kernel<<<dim3(768), 256, 0, stream>>>(bQh, bKh, bVt, bao);
  gemm_split_kernel<<<dim3(6, 64, 2), 256, 0, stream>>>(bao, Wo, Pwo, 768, 768, 384);
  reduce_kernel<2><<<3072, 256, 0, stream>>>(Pwo, x, fx1);

  // FFN sublayer
  rmsnorm_kernel<<<4096, 192, 0, stream>>>(fx1, g2, bxn);
  gemm_gu_kernel<<<dim3(32, 32), 256, 0, stream>>>(bxn, Wgate, Wup, bH);
  gemm_split_kernel<<<dim3(6, 64, 4), 256, 0, stream>>>(bH, Wdown, Pdn, 768, 2048, 512);
  reduce_kernel<4><<<3072, 256, 0, stream>>>(Pdn, fx1, out);
}